// Round 8
// baseline (183.219 us; speedup 1.0000x reference)
//
#include <hip/hip_runtime.h>
#include <math.h>

#define S_LEN 1024
#define D_DIM 64
#define NBH   16
#define CH    128          // t-chunk width
#define NCH   8            // chunks per row
#define RPB   14           // output rows per block (16-row tile - 2 halo)
#define NSB   74           // ceil(1024/14)

typedef unsigned short ushort_t;
typedef __attribute__((ext_vector_type(8))) short short8;   // 8 bf16 (4 VGPRs)
typedef __attribute__((ext_vector_type(4))) short short4v;  // 4 bf16 (8 B)
typedef __attribute__((ext_vector_type(4))) float f32x4;
typedef __attribute__((ext_vector_type(2))) float f32x2;    // -> v_pk_fma_f32

__device__ __forceinline__ ushort_t rne_bf16(float x) {
    unsigned u = __float_as_uint(x);
    return (ushort_t)((u + 0x7FFFu + ((u >> 16) & 1u)) >> 16);
}
__device__ __forceinline__ void split1(float x, ushort_t& h, ushort_t& l) {
    h = rne_bf16(x);
    float hf = __uint_as_float((unsigned)h << 16);
    l = rne_bf16(x - hf);
}

// ------------------------------ Prep ----------------------------------------
// blocks [0,512):    K split -> QK B-frag tiled layout, coalesced 16B writes
//                    khi[gid*8+j], gid = bh*8192 + tile*128 + ch*64 + lane,
//                    lane = quad*16 + (t&15); src K[bh][tile*16+t15][ch*32+quad*8+j]
// blocks [512,768):  V transpose-split -> PV B-frag tiled layout
// blocks [768,1024): mask bit-pack, thread-per-word
__global__ __launch_bounds__(256) void prep(
    const float* __restrict__ k, const float* __restrict__ v,
    const int* __restrict__ mask,
    ushort_t* __restrict__ khi, ushort_t* __restrict__ klo,
    ushort_t* __restrict__ vhi, ushort_t* __restrict__ vlo,
    unsigned* __restrict__ mw)
{
    __shared__ float Ls[64][65];
    const int tid = threadIdx.x;
    const int bx = blockIdx.x;
    if (bx < 512) {
        const int gid  = bx * 256 + tid;          // 0..131071
        const int bh   = gid >> 13;
        const int tile = (gid >> 7) & 63;
        const int ch   = (gid >> 6) & 1;
        const int lane = gid & 63;
        const int quad = lane >> 4, t15 = lane & 15;
        const float* src = k + ((size_t)bh * S_LEN + tile * 16 + t15) * D_DIM
                             + ch * 32 + quad * 8;
        float x[8];
        *(float4*)(x + 0) = *(const float4*)(src);
        *(float4*)(x + 4) = *(const float4*)(src + 4);
        short8 hv, lv;
        #pragma unroll
        for (int i = 0; i < 8; ++i) {
            ushort_t h, l;
            split1(x[i], h, l);
            hv[i] = (short)h; lv[i] = (short)l;
        }
        *(short8*)(khi + (size_t)gid * 8) = hv;
        *(short8*)(klo + (size_t)gid * 8) = lv;
    } else if (bx < 768) {
        const int bi = bx - 512;
        const int tt = bi & 15, bh = bi >> 4;
        const float* vb = v + ((size_t)bh * S_LEN + tt * 64) * D_DIM;
        #pragma unroll
        for (int p = 0; p < 4; ++p) {
            int idx = p * 1024 + tid * 4;
            int r = idx >> 6, c = idx & 63;
            float4 x = *(const float4*)(vb + r * 64 + c);
            Ls[r][c] = x.x; Ls[r][c+1] = x.y; Ls[r][c+2] = x.z; Ls[r][c+3] = x.w;
        }
        __syncthreads();
        const int d = tid >> 2, c0 = (tid & 3) * 16;
        ushort_t hi[16], lo[16];
        #pragma unroll
        for (int j = 0; j < 16; ++j) split1(Ls[c0 + j][d], hi[j], lo[j]);
        const int tb0 = tt * 8 + (c0 >> 3);
        const size_t o0 = (((size_t)bh * 128 + tb0) * 64 + d) * 8;
        const size_t o1 = (((size_t)bh * 128 + tb0 + 1) * 64 + d) * 8;
        *(short8*)(vhi + o0) = *(short8*)(hi);
        *(short8*)(vhi + o1) = *(short8*)(hi + 8);
        *(short8*)(vlo + o0) = *(short8*)(lo);
        *(short8*)(vlo + o1) = *(short8*)(lo + 8);
    } else {
        const int gid = (bx - 768) * 256 + tid;    // 0..65535
        const int row = gid >> 5, wd = gid & 31;   // row = b*1024+s
        const int4* mp = (const int4*)(mask + (size_t)row * 1024 + wd * 32);
        unsigned bits = 0;
        #pragma unroll
        for (int p = 0; p < 8; ++p) {
            int4 qv = mp[p];
            bits |= (qv.x != 0 ? 1u : 0u) << (p * 4 + 0);
            bits |= (qv.y != 0 ? 1u : 0u) << (p * 4 + 1);
            bits |= (qv.z != 0 ? 1u : 0u) << (p * 4 + 2);
            bits |= (qv.w != 0 ? 1u : 0u) << (p * 4 + 3);
        }
        mw[(size_t)row * 32 + wd] = bits;
    }
}

// ------------------ Fused: QK^T -> conv -> exp -> PV (deferred norm) ---------
// 512 threads = 8 waves. ONE barrier per iteration:
//   region j: [ QK(j) incl. own halos || PV(j-2) || conv+exp(j-1) ] barrier
// No online softmax: exp(pre) is fp32-safe (|pre| ~ O(10)); row-sum l kept
// per-thread in registers, reduced once in the epilogue.
__global__ __launch_bounds__(512) void fused_attn(
    const float* __restrict__ q,
    const ushort_t* __restrict__ khi, const ushort_t* __restrict__ klo,
    const ushort_t* __restrict__ vhi, const ushort_t* __restrict__ vlo,
    const unsigned* __restrict__ mw,
    const float* __restrict__ conv_w, const float* __restrict__ conv_b,
    const float* __restrict__ lin_w, const float* __restrict__ lin_b,
    float* __restrict__ out)
{
    __shared__ float dpS[2][16][132];        // halo: chunk col c at idx c+1
    __shared__ ushort_t pP[2][16 * 132];     // P bf16 (un-normalized exp)
    __shared__ float oBuf[16][68];           // epilogue partial merge
    __shared__ unsigned mb[14][32];          // mask bits
    __shared__ float lS[16];

    const int bs = blockIdx.x, bh = blockIdx.y;
    const int s0 = bs * RPB;
    const int b  = bh >> 3;
    const int tid = threadIdx.x;
    const int wave = tid >> 6, lane = tid & 63;
    const int m = lane & 15, quad = lane >> 4;

    if (tid < 448) {
        const int rr1 = tid >> 5, wd = tid & 31;
        const int s = s0 + rr1;               // row rr=rr1+1 -> s = s0-1+rr
        mb[rr1][wd] = (s < S_LEN) ? mw[((size_t)b * S_LEN + s) * 32 + wd] : 0u;
    }

    // conv params (uniform -> SGPRs)
    float w[36];
    #pragma unroll
    for (int i = 0; i < 36; ++i) w[i] = conv_w[i];
    float cb[4], lw[4];
    #pragma unroll
    for (int f = 0; f < 4; ++f) { cb[f] = conv_b[f]; lw[f] = lin_w[f]; }
    const float lb = lin_b[0];

    // Q A-fragments (rows s0-1+m, clamped; invalid rows zeroed at dp write)
    const int sA = s0 - 1 + m;
    const int sQ = sA < 0 ? 0 : (sA > S_LEN - 1 ? S_LEN - 1 : sA);
    const float* qp = q + ((size_t)bh * S_LEN + sQ) * D_DIM + quad * 8;
    float qa[16];
    *(float4*)(qa + 0)  = *(const float4*)(qp + 0);
    *(float4*)(qa + 4)  = *(const float4*)(qp + 4);
    *(float4*)(qa + 8)  = *(const float4*)(qp + 32);
    *(float4*)(qa + 12) = *(const float4*)(qp + 36);
    short8 ahi0, alo0, ahi1, alo1;
    #pragma unroll
    for (int i = 0; i < 8; ++i) {
        ushort_t h, l;
        split1(qa[i], h, l);      ahi0[i] = (short)h; alo0[i] = (short)l;
        split1(qa[8 + i], h, l);  ahi1[i] = (short)h; alo1[i] = (short)l;
    }

    // conv mapping: row rr=tid>>5 (0..15), col-group cg=tid&31 (4 cols each)
    const int rr = tid >> 5, cg = tid & 31;
    const bool act = rr >= 1 && rr <= RPB && (s0 - 1 + rr) < S_LEN;

    const int d0 = (wave & 3) * 16;           // PV d-range
    const int sbh = wave >> 2;                // PV sb half
    f32x4 O = {0.f, 0.f, 0.f, 0.f};
    float ls = 0.f;

    for (int j = 0; j <= NCH + 1; ++j) {      // 0..9
        // ---------------- QK chunk j -> slot j&1 (incl. halo cols) ----------
        if (j < NCH) {
            const int slot = j & 1;
            {   // main tile: wave w -> 16 cols at j*128 + w*16
                const int tile = j * 8 + wave;
                const size_t kb = ((size_t)bh * 8192 + tile * 128) + lane;
                short8 bhi0 = *(const short8*)(khi + kb * 8);
                short8 blo0 = *(const short8*)(klo + kb * 8);
                short8 bhi1 = *(const short8*)(khi + (kb + 64) * 8);
                short8 blo1 = *(const short8*)(klo + (kb + 64) * 8);
                f32x4 acc = {0.f, 0.f, 0.f, 0.f};
                acc = __builtin_amdgcn_mfma_f32_16x16x32_bf16(ahi0, bhi0, acc, 0, 0, 0);
                acc = __builtin_amdgcn_mfma_f32_16x16x32_bf16(ahi0, blo0, acc, 0, 0, 0);
                acc = __builtin_amdgcn_mfma_f32_16x16x32_bf16(alo0, bhi0, acc, 0, 0, 0);
                acc = __builtin_amdgcn_mfma_f32_16x16x32_bf16(ahi1, bhi1, acc, 0, 0, 0);
                acc = __builtin_amdgcn_mfma_f32_16x16x32_bf16(ahi1, blo1, acc, 0, 0, 0);
                acc = __builtin_amdgcn_mfma_f32_16x16x32_bf16(alo1, bhi1, acc, 0, 0, 0);
                const int col = wave * 16 + m;
                #pragma unroll
                for (int r = 0; r < 4; ++r) {
                    const int br = quad * 4 + r;
                    const int s  = s0 - 1 + br;
                    dpS[slot][br][col + 1] =
                        (s >= 0 && s < S_LEN) ? acc[r] * 0.125f : 0.f;
                }
            }
            if (wave == 0) {     // left halo col (idx 0)
                if (j == 0) {
                    if (lane < 16) dpS[0][lane][0] = 0.f;
                } else {
                    const int tile = j * 8 - 1;
                    const size_t kb = ((size_t)bh * 8192 + tile * 128) + lane;
                    short8 bhi0 = *(const short8*)(khi + kb * 8);
                    short8 blo0 = *(const short8*)(klo + kb * 8);
                    short8 bhi1 = *(const short8*)(khi + (kb + 64) * 8);
                    short8 blo1 = *(const short8*)(klo + (kb + 64) * 8);
                    f32x4 acc = {0.f, 0.f, 0.f, 0.f};
                    acc = __builtin_amdgcn_mfma_f32_16x16x32_bf16(ahi0, bhi0, acc, 0, 0, 0);
                    acc = __builtin_amdgcn_mfma_f32_16x16x32_bf16(ahi0, blo0, acc, 0, 0, 0);
                    acc = __builtin_amdgcn_mfma_f32_16x16x32_bf16(alo0, bhi0, acc, 0, 0, 0);
                    acc = __builtin_amdgcn_mfma_f32_16x16x32_bf16(ahi1, bhi1, acc, 0, 0, 0);
                    acc = __builtin_amdgcn_mfma_f32_16x16x32_bf16(ahi1, blo1, acc, 0, 0, 0);
                    acc = __builtin_amdgcn_mfma_f32_16x16x32_bf16(alo1, bhi1, acc, 0, 0, 0);
                    if (m == 15) {
                        #pragma unroll
                        for (int r = 0; r < 4; ++r) {
                            const int br = quad * 4 + r;
                            const int s  = s0 - 1 + br;
                            dpS[slot][br][0] =
                                (s >= 0 && s < S_LEN) ? acc[r] * 0.125f : 0.f;
                        }
                    }
                }
            }
            if (wave == 7) {     // right halo col (idx 129)
                if (j == NCH - 1) {
                    if (lane < 16) dpS[slot][lane][129] = 0.f;
                } else {
                    const int tile = j * 8 + 8;
                    const size_t kb = ((size_t)bh * 8192 + tile * 128) + lane;
                    short8 bhi0 = *(const short8*)(khi + kb * 8);
                    short8 blo0 = *(const short8*)(klo + kb * 8);
                    short8 bhi1 = *(const short8*)(khi + (kb + 64) * 8);
                    short8 blo1 = *(const short8*)(klo + (kb + 64) * 8);
                    f32x4 acc = {0.f, 0.f, 0.f, 0.f};
                    acc = __builtin_amdgcn_mfma_f32_16x16x32_bf16(ahi0, bhi0, acc, 0, 0, 0);
                    acc = __builtin_amdgcn_mfma_f32_16x16x32_bf16(ahi0, blo0, acc, 0, 0, 0);
                    acc = __builtin_amdgcn_mfma_f32_16x16x32_bf16(alo0, bhi0, acc, 0, 0, 0);
                    acc = __builtin_amdgcn_mfma_f32_16x16x32_bf16(ahi1, bhi1, acc, 0, 0, 0);
                    acc = __builtin_amdgcn_mfma_f32_16x16x32_bf16(ahi1, blo1, acc, 0, 0, 0);
                    acc = __builtin_amdgcn_mfma_f32_16x16x32_bf16(alo1, bhi1, acc, 0, 0, 0);
                    if (m == 0) {
                        #pragma unroll
                        for (int r = 0; r < 4; ++r) {
                            const int br = quad * 4 + r;
                            const int s  = s0 - 1 + br;
                            dpS[slot][br][129] =
                                (s >= 0 && s < S_LEN) ? acc[r] * 0.125f : 0.f;
                        }
                    }
                }
            }
        }

        // ---------------- PV on chunk c2 = j-2 ------------------------------
        if (j >= 2) {
            const int c2 = j - 2, p2 = c2 & 1;
            #pragma unroll
            for (int sbi = 0; sbi < 2; ++sbi) {
                const int sb = sbh * 2 + sbi;
                short8 ph = *(const short8*)&pP[p2][m * 132 + sb * 32 + quad * 8];
                const size_t vb = (((size_t)bh * 128 + c2 * 16 + sb * 4 + quad) * 64 + d0 + m) * 8;
                short8 vh = *(const short8*)(vhi + vb);
                short8 vl = *(const short8*)(vlo + vb);
                O = __builtin_amdgcn_mfma_f32_16x16x32_bf16(ph, vh, O, 0, 0, 0);
                O = __builtin_amdgcn_mfma_f32_16x16x32_bf16(ph, vl, O, 0, 0, 0);
            }
        }

        // ---------------- conv + mask + exp on chunk c = j-1 ----------------
        if (j >= 1 && j <= NCH && act) {
            const int c = j - 1, pc = c & 1;
            float vv[3][6];
            #pragma unroll
            for (int dr = 0; dr < 3; ++dr) {
                const float* rp = &dpS[pc][rr - 1 + dr][cg * 4];
                f32x4 a0 = *(const f32x4*)(rp);
                f32x2 a1 = *(const f32x2*)(rp + 4);
                vv[dr][0] = a0.x; vv[dr][1] = a0.y; vv[dr][2] = a0.z;
                vv[dr][3] = a0.w; vv[dr][4] = a1.x; vv[dr][5] = a1.y;
            }
            f32x2 pa = {lb, lb}, pb = {lb, lb};
            #pragma unroll
            for (int f = 0; f < 4; ++f) {
                f32x2 ca = {cb[f], cb[f]}, cbv = ca;
                #pragma unroll
                for (int dr = 0; dr < 3; ++dr) {
                    #pragma unroll
                    for (int dc = 0; dc < 3; ++dc) {
                        const float wt = w[f * 9 + dr * 3 + dc];
                        f32x2 ia = {vv[dr][dc],     vv[dr][dc + 1]};
                        f32x2 ib = {vv[dr][dc + 2], vv[dr][dc + 3]};
                        ca  += wt * ia;
                        cbv += wt * ib;
                    }
                }
                f32x2 la  = {fmaxf(ca.x, 0.f)  + 0.01f * fminf(ca.x, 0.f),
                             fmaxf(ca.y, 0.f)  + 0.01f * fminf(ca.y, 0.f)};
                f32x2 lb2 = {fmaxf(cbv.x, 0.f) + 0.01f * fminf(cbv.x, 0.f),
                             fmaxf(cbv.y, 0.f) + 0.01f * fminf(cbv.y, 0.f)};
                pa += lw[f] * la;
                pb += lw[f] * lb2;
            }
            const unsigned word = mb[rr - 1][c * 4 + (cg >> 3)];
            const unsigned nib  = (word >> ((cg & 7) * 4)) & 0xFu;
            float pre[4] = {pa.x, pa.y, pb.x, pb.y};
            #pragma unroll
            for (int i = 0; i < 4; ++i)
                if (!((nib >> i) & 1u)) pre[i] = -1e30f;
            float pv[4];
            #pragma unroll
            for (int i = 0; i < 4; ++i) { pv[i] = __expf(pre[i]); ls += pv[i]; }
            short4v hv = {(short)rne_bf16(pv[0]), (short)rne_bf16(pv[1]),
                          (short)rne_bf16(pv[2]), (short)rne_bf16(pv[3])};
            *(short4v*)&pP[pc][rr * 132 + cg * 4] = hv;
        }
        __syncthreads();
    }

    // ---------------------------- epilogue ----------------------------------
    // reduce per-thread row-sums across the 32 col-group threads of each row
    float l = ls;
    #pragma unroll
    for (int off = 1; off < 32; off <<= 1) l += __shfl_xor(l, off);
    if (cg == 0 && rr >= 1 && rr <= RPB) lS[rr] = l;
    if (wave < 4) {
        #pragma unroll
        for (int r = 0; r < 4; ++r) oBuf[quad * 4 + r][d0 + m] = O[r];
    }
    __syncthreads();
    if (wave >= 4) {
        #pragma unroll
        for (int r = 0; r < 4; ++r) {
            const int br = quad * 4 + r;
            const int s = s0 - 1 + br;
            if (br >= 1 && br <= RPB && s < S_LEN)
                out[((size_t)bh * S_LEN + s) * D_DIM + d0 + m] =
                    (O[r] + oBuf[br][d0 + m]) / lS[br];
        }
    }
}

extern "C" void kernel_launch(void* const* d_in, const int* in_sizes, int n_in,
                              void* d_out, int out_size, void* d_ws, size_t ws_size,
                              hipStream_t stream) {
    const float* q      = (const float*)d_in[0];
    const float* k      = (const float*)d_in[1];
    const float* v      = (const float*)d_in[2];
    const int*   mask   = (const int*)d_in[3];
    const float* conv_w = (const float*)d_in[4];
    const float* conv_b = (const float*)d_in[5];
    const float* lin_w  = (const float*)d_in[6];
    const float* lin_b  = (const float*)d_in[7];
    float* out = (float*)d_out;

    char* wsb = (char*)d_ws;
    const size_t MB = 1024 * 1024;
    ushort_t* khi = (ushort_t*)(wsb + 0 * MB);
    ushort_t* klo = (ushort_t*)(wsb + 2 * MB);
    ushort_t* vhi = (ushort_t*)(wsb + 4 * MB);
    ushort_t* vlo = (ushort_t*)(wsb + 6 * MB);
    unsigned* mw  = (unsigned*)(wsb + 8 * MB);

    prep<<<dim3(1024), 256, 0, stream>>>(k, v, mask, khi, klo, vhi, vlo, mw);
    fused_attn<<<dim3(NSB, NBH), 512, 0, stream>>>(
        q, khi, klo, vhi, vlo, mw,
        conv_w, conv_b, lin_w, lin_b, out);
}

// Round 9
// 149.693 us; speedup vs baseline: 1.2240x; 1.2240x over previous
//
#include <hip/hip_runtime.h>
#include <math.h>

#define S_LEN 1024
#define D_DIM 64
#define NBH   16

typedef unsigned short ushort_t;
typedef __attribute__((ext_vector_type(8))) short short8;   // 8 bf16 (4 VGPRs)
typedef __attribute__((ext_vector_type(4))) short short4v;  // 4 bf16 (8 B)
typedef __attribute__((ext_vector_type(4))) float f32x4;
typedef __attribute__((ext_vector_type(2))) float f32x2;

__device__ __forceinline__ ushort_t rne_bf16(float x) {
    unsigned u = __float_as_uint(x);
    return (ushort_t)((u + 0x7FFFu + ((u >> 16) & 1u)) >> 16);
}
__device__ __forceinline__ void split1(float x, ushort_t& h, ushort_t& l) {
    h = rne_bf16(x);
    float hf = __uint_as_float((unsigned)h << 16);
    l = rne_bf16(x - hf);
}

// ------------------------------ Prep ----------------------------------------
// blocks [0,512):    K split -> QK B-frag tiled layout (coalesced 16B writes)
// blocks [512,768):  V transpose-split -> PV B-frag tiled layout
// blocks [768,1024): mask bit-pack, thread-per-word
__global__ __launch_bounds__(256) void prep(
    const float* __restrict__ k, const float* __restrict__ v,
    const int* __restrict__ mask,
    ushort_t* __restrict__ khi, ushort_t* __restrict__ klo,
    ushort_t* __restrict__ vhi, ushort_t* __restrict__ vlo,
    unsigned* __restrict__ mw)
{
    __shared__ float Ls[64][65];
    const int tid = threadIdx.x;
    const int bx = blockIdx.x;
    if (bx < 512) {
        const int gid  = bx * 256 + tid;          // 0..131071
        const int bh   = gid >> 13;
        const int tile = (gid >> 7) & 63;
        const int ch   = (gid >> 6) & 1;
        const int lane = gid & 63;
        const int quad = lane >> 4, t15 = lane & 15;
        const float* src = k + ((size_t)bh * S_LEN + tile * 16 + t15) * D_DIM
                             + ch * 32 + quad * 8;
        float x[8];
        *(float4*)(x + 0) = *(const float4*)(src);
        *(float4*)(x + 4) = *(const float4*)(src + 4);
        short8 hv, lv;
        #pragma unroll
        for (int i = 0; i < 8; ++i) {
            ushort_t h, l;
            split1(x[i], h, l);
            hv[i] = (short)h; lv[i] = (short)l;
        }
        *(short8*)(khi + (size_t)gid * 8) = hv;
        *(short8*)(klo + (size_t)gid * 8) = lv;
    } else if (bx < 768) {
        const int bi = bx - 512;
        const int tt = bi & 15, bh = bi >> 4;
        const float* vb = v + ((size_t)bh * S_LEN + tt * 64) * D_DIM;
        #pragma unroll
        for (int p = 0; p < 4; ++p) {
            int idx = p * 1024 + tid * 4;
            int r = idx >> 6, c = idx & 63;
            float4 x = *(const float4*)(vb + r * 64 + c);
            Ls[r][c] = x.x; Ls[r][c+1] = x.y; Ls[r][c+2] = x.z; Ls[r][c+3] = x.w;
        }
        __syncthreads();
        const int d = tid >> 2, c0 = (tid & 3) * 16;
        ushort_t hi[16], lo[16];
        #pragma unroll
        for (int j = 0; j < 16; ++j) split1(Ls[c0 + j][d], hi[j], lo[j]);
        const int tb0 = tt * 8 + (c0 >> 3);
        const size_t o0 = (((size_t)bh * 128 + tb0) * 64 + d) * 8;
        const size_t o1 = (((size_t)bh * 128 + tb0 + 1) * 64 + d) * 8;
        *(short8*)(vhi + o0) = *(short8*)(hi);
        *(short8*)(vhi + o1) = *(short8*)(hi + 8);
        *(short8*)(vlo + o0) = *(short8*)(lo);
        *(short8*)(vlo + o1) = *(short8*)(lo + 8);
    } else {
        const int gid = (bx - 768) * 256 + tid;    // 0..65535
        const int row = gid >> 5, wd = gid & 31;   // row = b*1024+s
        const int4* mp = (const int4*)(mask + (size_t)row * 1024 + wd * 32);
        unsigned bits = 0;
        #pragma unroll
        for (int p = 0; p < 8; ++p) {
            int4 qv = mp[p];
            bits |= (qv.x != 0 ? 1u : 0u) << (p * 4 + 0);
            bits |= (qv.y != 0 ? 1u : 0u) << (p * 4 + 1);
            bits |= (qv.z != 0 ? 1u : 0u) << (p * 4 + 2);
            bits |= (qv.w != 0 ? 1u : 0u) << (p * 4 + 3);
        }
        mw[(size_t)row * 32 + wd] = bits;
    }
}

// ---------- K1: dp[bh,s,t] = (1/8) Q.K^T, MFMA, no barriers -----------------
// grid (4 t-strips, 64 s-tiles, 16 bh), block 256 = 4 waves.
// wave w handles tiles strip*16 + w*4 .. +3 (64 cols), 16 rows.
__global__ __launch_bounds__(256) void qk_mfma(
    const float* __restrict__ q,
    const ushort_t* __restrict__ khi, const ushort_t* __restrict__ klo,
    float* __restrict__ dp)
{
    const int strip = blockIdx.x, st = blockIdx.y, bh = blockIdx.z;
    const int s0 = st * 16;
    const int tid = threadIdx.x;
    const int wave = tid >> 6, lane = tid & 63;
    const int m = lane & 15, quad = lane >> 4;

    // A fragments: Q rows s0+m
    const float* qp = q + ((size_t)bh * S_LEN + s0 + m) * D_DIM + quad * 8;
    float qa[16];
    *(float4*)(qa + 0)  = *(const float4*)(qp + 0);
    *(float4*)(qa + 4)  = *(const float4*)(qp + 4);
    *(float4*)(qa + 8)  = *(const float4*)(qp + 32);
    *(float4*)(qa + 12) = *(const float4*)(qp + 36);
    short8 ahi0, alo0, ahi1, alo1;
    #pragma unroll
    for (int i = 0; i < 8; ++i) {
        ushort_t h, l;
        split1(qa[i], h, l);      ahi0[i] = (short)h; alo0[i] = (short)l;
        split1(qa[8 + i], h, l);  ahi1[i] = (short)h; alo1[i] = (short)l;
    }

    const int tile0 = strip * 16 + wave * 4;
    float* dpb = dp + ((size_t)bh * S_LEN + s0) * S_LEN;
    #pragma unroll
    for (int tt = 0; tt < 4; ++tt) {
        const int tile = tile0 + tt;
        const size_t kb = ((size_t)bh * 8192 + tile * 128) + lane;
        short8 bhi0 = *(const short8*)(khi + kb * 8);
        short8 blo0 = *(const short8*)(klo + kb * 8);
        short8 bhi1 = *(const short8*)(khi + (kb + 64) * 8);
        short8 blo1 = *(const short8*)(klo + (kb + 64) * 8);
        f32x4 acc = {0.f, 0.f, 0.f, 0.f};
        acc = __builtin_amdgcn_mfma_f32_16x16x32_bf16(ahi0, bhi0, acc, 0, 0, 0);
        acc = __builtin_amdgcn_mfma_f32_16x16x32_bf16(ahi0, blo0, acc, 0, 0, 0);
        acc = __builtin_amdgcn_mfma_f32_16x16x32_bf16(alo0, bhi0, acc, 0, 0, 0);
        acc = __builtin_amdgcn_mfma_f32_16x16x32_bf16(ahi1, bhi1, acc, 0, 0, 0);
        acc = __builtin_amdgcn_mfma_f32_16x16x32_bf16(ahi1, blo1, acc, 0, 0, 0);
        acc = __builtin_amdgcn_mfma_f32_16x16x32_bf16(alo1, bhi1, acc, 0, 0, 0);
        const int t0 = tile * 16;
        #pragma unroll
        for (int r = 0; r < 4; ++r)
            dpb[(size_t)(quad * 4 + r) * S_LEN + t0 + m] = acc[r] * 0.125f;
    }
}

// ---------- K2: conv(3x3,4f)+leaky+linear+mask+exp+normalize -> bf16 attn ----
// grid (128 row-groups, 16 bh), block 256. 8 output rows/block via LDS.
// LDS row stride 1032 floats; data col t at idx t; idx 1024..1031 zeroed
// (right-halo zero at 1024, left-halo zero source at 1028).
#define RS2 1032
__global__ __launch_bounds__(256) void conv_softmax(
    const float* __restrict__ dp, const unsigned* __restrict__ mw,
    const float* __restrict__ conv_w, const float* __restrict__ conv_b,
    const float* __restrict__ lin_w, const float* __restrict__ lin_b,
    ushort_t* __restrict__ attn)
{
    __shared__ float rows[10 * RS2];     // 41.3 KB
    const int r0 = blockIdx.x * 8, bh = blockIdx.y;
    const int b  = bh >> 3;
    const int tid = threadIdx.x;

    const float* base = dp + (size_t)bh * S_LEN * S_LEN;
    #pragma unroll
    for (int seg = 0; seg < 10; ++seg) {
        const int sr = r0 - 1 + seg;
        float4 val = make_float4(0.f, 0.f, 0.f, 0.f);
        if (sr >= 0 && sr < S_LEN)
            val = *(const float4*)(base + (size_t)sr * S_LEN + tid * 4);
        *(float4*)&rows[seg * RS2 + tid * 4] = val;
    }
    if (tid < 80) rows[(tid >> 3) * RS2 + 1024 + (tid & 7)] = 0.f;

    float w[36];
    #pragma unroll
    for (int i = 0; i < 36; ++i) w[i] = conv_w[i];
    float cb[4], lw[4];
    #pragma unroll
    for (int f = 0; f < 4; ++f) { cb[f] = conv_b[f]; lw[f] = lin_w[f]; }
    const float lb = lin_b[0];
    __syncthreads();

    const int r = tid >> 5, cg = tid & 31;
    const int srow = r0 + r;
    const unsigned mword = mw[((size_t)b * S_LEN + srow) * 32 + cg];
    float pvv[8][4];
    float ls = 0.f;

    #pragma unroll
    for (int g = 0; g < 8; ++g) {
        const int c0 = cg * 4 + 128 * g;
        const int li = c0 ? c0 - 1 : 1028;          // left halo (zero slot)
        float vv[3][6];
        #pragma unroll
        for (int dr = 0; dr < 3; ++dr) {
            const float* rp = &rows[(r + dr) * RS2];
            f32x4 md = *(const f32x4*)(rp + c0);
            vv[dr][0] = rp[li];
            vv[dr][1] = md.x; vv[dr][2] = md.y; vv[dr][3] = md.z; vv[dr][4] = md.w;
            vv[dr][5] = rp[c0 + 4];
        }
        f32x2 pa = {lb, lb}, pb = {lb, lb};
        #pragma unroll
        for (int f = 0; f < 4; ++f) {
            f32x2 ca = {cb[f], cb[f]}, cbv = ca;
            #pragma unroll
            for (int dr = 0; dr < 3; ++dr) {
                #pragma unroll
                for (int dc = 0; dc < 3; ++dc) {
                    const float wt = w[f * 9 + dr * 3 + dc];
                    f32x2 ia = {vv[dr][dc],     vv[dr][dc + 1]};
                    f32x2 ib = {vv[dr][dc + 2], vv[dr][dc + 3]};
                    ca  += wt * ia;
                    cbv += wt * ib;
                }
            }
            f32x2 la  = {fmaxf(ca.x, 0.f)  + 0.01f * fminf(ca.x, 0.f),
                         fmaxf(ca.y, 0.f)  + 0.01f * fminf(ca.y, 0.f)};
            f32x2 lb2 = {fmaxf(cbv.x, 0.f) + 0.01f * fminf(cbv.x, 0.f),
                         fmaxf(cbv.y, 0.f) + 0.01f * fminf(cbv.y, 0.f)};
            pa += lw[f] * la;
            pb += lw[f] * lb2;
        }
        // mask nibble: bit i of group (g*4+cg/8... word covers cols [cg*32? no:
        // word = mw[..+cg] covers cols cg*32 .. cg*32+31?  NO: packing is
        // col = wd*32 + bit, so col c0+i -> wd = (c0+i)>>5, bit = (c0+i)&31.
        // c0 = cg*4+128g -> wd = (cg>>3)+4g, bit = (cg&7)*4+i.  Reload per g:
        float pre[4] = {pa.x, pa.y, pb.x, pb.y};
        const unsigned word2 = mw[((size_t)b * S_LEN + srow) * 32 + (cg >> 3) + 4 * g];
        const unsigned nib = (word2 >> ((cg & 7) * 4)) & 0xFu;
        #pragma unroll
        for (int i = 0; i < 4; ++i)
            if (!((nib >> i) & 1u)) pre[i] = -1e30f;
        #pragma unroll
        for (int i = 0; i < 4; ++i) { pvv[g][i] = __expf(pre[i]); ls += pvv[g][i]; }
    }
    (void)mword;

    // reduce row sum across the 32 col threads (lanes 0-31 / 32-63 = two rows)
    #pragma unroll
    for (int off = 1; off < 32; off <<= 1) ls += __shfl_xor(ls, off);
    const float inv = 1.0f / ls;

    ushort_t* arow = attn + ((size_t)bh * S_LEN + srow) * S_LEN;
    #pragma unroll
    for (int g = 0; g < 8; ++g) {
        const int c0 = cg * 4 + 128 * g;
        short4v hv = {(short)rne_bf16(pvv[g][0] * inv), (short)rne_bf16(pvv[g][1] * inv),
                      (short)rne_bf16(pvv[g][2] * inv), (short)rne_bf16(pvv[g][3] * inv)};
        *(short4v*)(arow + c0) = hv;
    }
}

// ---------- K3: out = attn @ V, MFMA, attn staged via LDS -------------------
// grid (64 s-tiles, 16 bh), block 256 = 4 waves; wave w -> d-range w*16.
#define AS3 1032   // LDS attn row stride (ushorts)
__global__ __launch_bounds__(256) void av_mfma(
    const ushort_t* __restrict__ attn,
    const ushort_t* __restrict__ vhi, const ushort_t* __restrict__ vlo,
    float* __restrict__ out)
{
    __shared__ ushort_t aS[16 * AS3];    // 33 KB
    const int st = blockIdx.x, bh = blockIdx.y;
    const int s0 = st * 16;
    const int tid = threadIdx.x;
    const int wave = tid >> 6, lane = tid & 63;
    const int m = lane & 15, quad = lane >> 4;

    // stage 16 rows x 1024 bf16 (2048 B each): 8 iters x 256 thr x 16 B
    const ushort_t* ab = attn + ((size_t)bh * S_LEN + s0) * S_LEN;
    #pragma unroll
    for (int it = 0; it < 8; ++it) {
        const int idx = it * 256 + tid;       // 0..2047
        const int row = idx >> 7, chunk = idx & 127;
        *(short8*)&aS[row * AS3 + chunk * 8] =
            *(const short8*)(ab + (size_t)row * S_LEN + chunk * 8);
    }
    __syncthreads();

    const int d0 = wave * 16;
    f32x4 O = {0.f, 0.f, 0.f, 0.f};
    #pragma unroll 4
    for (int c = 0; c < 32; ++c) {           // 32-t chunks
        short8 ph = *(const short8*)&aS[m * AS3 + c * 32 + quad * 8];
        const size_t vb = (((size_t)bh * 128 + c * 4 + quad) * 64 + d0 + m) * 8;
        short8 vh = *(const short8*)(vhi + vb);
        short8 vl = *(const short8*)(vlo + vb);
        O = __builtin_amdgcn_mfma_f32_16x16x32_bf16(ph, vh, O, 0, 0, 0);
        O = __builtin_amdgcn_mfma_f32_16x16x32_bf16(ph, vl, O, 0, 0, 0);
    }
    #pragma unroll
    for (int r = 0; r < 4; ++r)
        out[((size_t)bh * S_LEN + s0 + quad * 4 + r) * D_DIM + d0 + m] = O[r];
}

extern "C" void kernel_launch(void* const* d_in, const int* in_sizes, int n_in,
                              void* d_out, int out_size, void* d_ws, size_t ws_size,
                              hipStream_t stream) {
    const float* q      = (const float*)d_in[0];
    const float* k      = (const float*)d_in[1];
    const float* v      = (const float*)d_in[2];
    const int*   mask   = (const int*)d_in[3];
    const float* conv_w = (const float*)d_in[4];
    const float* conv_b = (const float*)d_in[5];
    const float* lin_w  = (const float*)d_in[6];
    const float* lin_b  = (const float*)d_in[7];
    float* out = (float*)d_out;

    char* wsb = (char*)d_ws;
    const size_t MB = 1024 * 1024;
    ushort_t* khi  = (ushort_t*)(wsb + 0 * MB);
    ushort_t* klo  = (ushort_t*)(wsb + 2 * MB);
    ushort_t* vhi  = (ushort_t*)(wsb + 4 * MB);
    ushort_t* vlo  = (ushort_t*)(wsb + 6 * MB);
    unsigned* mw   = (unsigned*)(wsb + 8 * MB);
    float*    dp   = (float*)(wsb + 16 * MB);      // 64 MiB
    ushort_t* attn = (ushort_t*)(wsb + 80 * MB);   // 32 MiB

    prep<<<dim3(1024), 256, 0, stream>>>(k, v, mask, khi, klo, vhi, vlo, mw);
    qk_mfma<<<dim3(4, 64, NBH), 256, 0, stream>>>(q, khi, klo, dp);
    conv_softmax<<<dim3(128, NBH), 256, 0, stream>>>(
        dp, mw, conv_w, conv_b, lin_w, lin_b, attn);
    av_mfma<<<dim3(64, NBH), 256, 0, stream>>>(attn, vhi, vlo, out);
}

// Round 10
// 142.010 us; speedup vs baseline: 1.2902x; 1.0541x over previous
//
#include <hip/hip_runtime.h>
#include <math.h>

#define S_LEN 1024
#define D_DIM 64
#define NBH   16

typedef unsigned short ushort_t;
typedef __attribute__((ext_vector_type(8))) short short8;   // 8 bf16 (4 VGPRs)
typedef __attribute__((ext_vector_type(4))) short short4v;  // 4 bf16 (8 B)
typedef __attribute__((ext_vector_type(4))) float f32x4;
typedef __attribute__((ext_vector_type(2))) float f32x2;

__device__ __forceinline__ ushort_t rne_bf16(float x) {
    unsigned u = __float_as_uint(x);
    return (ushort_t)((u + 0x7FFFu + ((u >> 16) & 1u)) >> 16);
}
__device__ __forceinline__ void split1(float x, ushort_t& h, ushort_t& l) {
    h = rne_bf16(x);
    float hf = __uint_as_float((unsigned)h << 16);
    l = rne_bf16(x - hf);
}

// ------------------------------ Prep ----------------------------------------
// blocks [0,512):    K split -> QK B-frag tiled layout (coalesced 16B writes)
// blocks [512,768):  V transpose-split -> PV B-frag tiled layout
// blocks [768,1024): mask bit-pack, thread-per-word
__global__ __launch_bounds__(256) void prep(
    const float* __restrict__ k, const float* __restrict__ v,
    const int* __restrict__ mask,
    ushort_t* __restrict__ khi, ushort_t* __restrict__ klo,
    ushort_t* __restrict__ vhi, ushort_t* __restrict__ vlo,
    unsigned* __restrict__ mw)
{
    __shared__ float Ls[64][65];
    const int tid = threadIdx.x;
    const int bx = blockIdx.x;
    if (bx < 512) {
        const int gid  = bx * 256 + tid;          // 0..131071
        const int bh   = gid >> 13;
        const int tile = (gid >> 7) & 63;
        const int ch   = (gid >> 6) & 1;
        const int lane = gid & 63;
        const int quad = lane >> 4, t15 = lane & 15;
        const float* src = k + ((size_t)bh * S_LEN + tile * 16 + t15) * D_DIM
                             + ch * 32 + quad * 8;
        float x[8];
        *(float4*)(x + 0) = *(const float4*)(src);
        *(float4*)(x + 4) = *(const float4*)(src + 4);
        short8 hv, lv;
        #pragma unroll
        for (int i = 0; i < 8; ++i) {
            ushort_t h, l;
            split1(x[i], h, l);
            hv[i] = (short)h; lv[i] = (short)l;
        }
        *(short8*)(khi + (size_t)gid * 8) = hv;
        *(short8*)(klo + (size_t)gid * 8) = lv;
    } else if (bx < 768) {
        const int bi = bx - 512;
        const int tt = bi & 15, bh = bi >> 4;
        const float* vb = v + ((size_t)bh * S_LEN + tt * 64) * D_DIM;
        #pragma unroll
        for (int p = 0; p < 4; ++p) {
            int idx = p * 1024 + tid * 4;
            int r = idx >> 6, c = idx & 63;
            float4 x = *(const float4*)(vb + r * 64 + c);
            Ls[r][c] = x.x; Ls[r][c+1] = x.y; Ls[r][c+2] = x.z; Ls[r][c+3] = x.w;
        }
        __syncthreads();
        const int d = tid >> 2, c0 = (tid & 3) * 16;
        ushort_t hi[16], lo[16];
        #pragma unroll
        for (int j = 0; j < 16; ++j) split1(Ls[c0 + j][d], hi[j], lo[j]);
        const int tb0 = tt * 8 + (c0 >> 3);
        const size_t o0 = (((size_t)bh * 128 + tb0) * 64 + d) * 8;
        const size_t o1 = (((size_t)bh * 128 + tb0 + 1) * 64 + d) * 8;
        *(short8*)(vhi + o0) = *(short8*)(hi);
        *(short8*)(vhi + o1) = *(short8*)(hi + 8);
        *(short8*)(vlo + o0) = *(short8*)(lo);
        *(short8*)(vlo + o1) = *(short8*)(lo + 8);
    } else {
        const int gid = (bx - 768) * 256 + tid;    // 0..65535
        const int row = gid >> 5, wd = gid & 31;   // row = b*1024+s
        const int4* mp = (const int4*)(mask + (size_t)row * 1024 + wd * 32);
        unsigned bits = 0;
        #pragma unroll
        for (int p = 0; p < 8; ++p) {
            int4 qv = mp[p];
            bits |= (qv.x != 0 ? 1u : 0u) << (p * 4 + 0);
            bits |= (qv.y != 0 ? 1u : 0u) << (p * 4 + 1);
            bits |= (qv.z != 0 ? 1u : 0u) << (p * 4 + 2);
            bits |= (qv.w != 0 ? 1u : 0u) << (p * 4 + 3);
        }
        mw[(size_t)row * 32 + wd] = bits;
    }
}

// ---------- K1: dp[bh,s,t] = (1/8) Q.K^T, MFMA, no barriers -----------------
// grid (4 t-strips, 64 s-tiles, 16 bh), block 256 = 4 waves.
__global__ __launch_bounds__(256) void qk_mfma(
    const float* __restrict__ q,
    const ushort_t* __restrict__ khi, const ushort_t* __restrict__ klo,
    float* __restrict__ dp)
{
    const int strip = blockIdx.x, st = blockIdx.y, bh = blockIdx.z;
    const int s0 = st * 16;
    const int tid = threadIdx.x;
    const int wave = tid >> 6, lane = tid & 63;
    const int m = lane & 15, quad = lane >> 4;

    const float* qp = q + ((size_t)bh * S_LEN + s0 + m) * D_DIM + quad * 8;
    float qa[16];
    *(float4*)(qa + 0)  = *(const float4*)(qp + 0);
    *(float4*)(qa + 4)  = *(const float4*)(qp + 4);
    *(float4*)(qa + 8)  = *(const float4*)(qp + 32);
    *(float4*)(qa + 12) = *(const float4*)(qp + 36);
    short8 ahi0, alo0, ahi1, alo1;
    #pragma unroll
    for (int i = 0; i < 8; ++i) {
        ushort_t h, l;
        split1(qa[i], h, l);      ahi0[i] = (short)h; alo0[i] = (short)l;
        split1(qa[8 + i], h, l);  ahi1[i] = (short)h; alo1[i] = (short)l;
    }

    const int tile0 = strip * 16 + wave * 4;
    float* dpb = dp + ((size_t)bh * S_LEN + s0) * S_LEN;
    #pragma unroll
    for (int tt = 0; tt < 4; ++tt) {
        const int tile = tile0 + tt;
        const size_t kb = ((size_t)bh * 8192 + tile * 128) + lane;
        short8 bhi0 = *(const short8*)(khi + kb * 8);
        short8 blo0 = *(const short8*)(klo + kb * 8);
        short8 bhi1 = *(const short8*)(khi + (kb + 64) * 8);
        short8 blo1 = *(const short8*)(klo + (kb + 64) * 8);
        f32x4 acc = {0.f, 0.f, 0.f, 0.f};
        acc = __builtin_amdgcn_mfma_f32_16x16x32_bf16(ahi0, bhi0, acc, 0, 0, 0);
        acc = __builtin_amdgcn_mfma_f32_16x16x32_bf16(ahi0, blo0, acc, 0, 0, 0);
        acc = __builtin_amdgcn_mfma_f32_16x16x32_bf16(alo0, bhi0, acc, 0, 0, 0);
        acc = __builtin_amdgcn_mfma_f32_16x16x32_bf16(ahi1, bhi1, acc, 0, 0, 0);
        acc = __builtin_amdgcn_mfma_f32_16x16x32_bf16(ahi1, blo1, acc, 0, 0, 0);
        acc = __builtin_amdgcn_mfma_f32_16x16x32_bf16(alo1, bhi1, acc, 0, 0, 0);
        const int t0 = tile * 16;
        #pragma unroll
        for (int r = 0; r < 4; ++r)
            dpb[(size_t)(quad * 4 + r) * S_LEN + t0 + m] = acc[r] * 0.125f;
    }
}

// ---------- K2: conv+leaky+linear+mask+exp  ->  PV MFMA (fused, phased) ------
// grid (64 s-tiles, 16 bh), block 512 = 8 waves. LDS ~79 KB -> 2 blocks/CU.
// Phase A: stage dp rows s0-1..s0+8; conv rows 0-7 (wave w = row w).
// Phase B: stage dp rows s0+7..s0+16; conv rows 8-15.
// Phase C: PV. wave w: d0=(w&3)*16, t-half w>>2; partials merged via oBuf.
// P is unnormalized exp() bf16 in LDS; 1/rowsum folded into epilogue.
#define BUFS 1032   // dp stage row stride (floats)
#define PSTR 1040   // pP row stride (ushorts)
__global__ __launch_bounds__(512) void conv_av(
    const float* __restrict__ dp, const unsigned* __restrict__ mw,
    const ushort_t* __restrict__ vhi, const ushort_t* __restrict__ vlo,
    const float* __restrict__ conv_w, const float* __restrict__ conv_b,
    const float* __restrict__ lin_w, const float* __restrict__ lin_b,
    float* __restrict__ out)
{
    __shared__ float buf[10 * BUFS];       // 41.3 KB
    __shared__ ushort_t pP[16 * PSTR];     // 33.3 KB
    __shared__ float oBuf[16][68];         // 4.4 KB
    __shared__ float lS[16];

    const int st = blockIdx.x, bh = blockIdx.y;
    const int s0 = st * 16;
    const int b  = bh >> 3;
    const int tid = threadIdx.x;
    const int wave = tid >> 6, lane = tid & 63;
    const int m = lane & 15, quad = lane >> 4;

    float w[36];
    #pragma unroll
    for (int i = 0; i < 36; ++i) w[i] = conv_w[i];
    float cb[4], lw[4];
    #pragma unroll
    for (int f = 0; f < 4; ++f) { cb[f] = conv_b[f]; lw[f] = lin_w[f]; }
    const float lb = lin_b[0];

    const float* base = dp + (size_t)bh * S_LEN * S_LEN;

    #pragma unroll
    for (int phase = 0; phase < 2; ++phase) {
        // ---- stage 10 dp rows: phase A rows s0-1.., phase B rows s0+7.. ----
        const int sbase = s0 - 1 + phase * 8;
        #pragma unroll
        for (int it = 0; it < 5; ++it) {
            const int idx = it * 512 + tid;       // 0..2559
            const int row = idx >> 8, c4 = idx & 255;
            const int sr = sbase + row;
            float4 val = make_float4(0.f, 0.f, 0.f, 0.f);
            if (sr >= 0 && sr < S_LEN)
                val = *(const float4*)(base + (size_t)sr * S_LEN + c4 * 4);
            *(float4*)&buf[row * BUFS + c4 * 4] = val;
        }
        if (tid < 80) buf[(tid >> 3) * BUFS + 1024 + (tid & 7)] = 0.f;
        __syncthreads();

        // ---- conv + mask + exp: wave w -> out row r = phase*8 + w ----------
        const int r = phase * 8 + wave;
        const int srow = s0 + r;
        float ls = 0.f;
        #pragma unroll
        for (int g = 0; g < 4; ++g) {
            const int c0 = lane * 4 + 256 * g;
            const int li = c0 ? c0 - 1 : 1028;    // zero slot for left halo
            float vv[3][6];
            #pragma unroll
            for (int dr = 0; dr < 3; ++dr) {
                const float* rp = &buf[(wave + dr) * BUFS];
                f32x4 md = *(const f32x4*)(rp + c0);
                vv[dr][0] = rp[li];
                vv[dr][1] = md.x; vv[dr][2] = md.y; vv[dr][3] = md.z; vv[dr][4] = md.w;
                vv[dr][5] = rp[c0 + 4];
            }
            f32x2 pa = {lb, lb}, pb = {lb, lb};
            #pragma unroll
            for (int f = 0; f < 4; ++f) {
                f32x2 ca = {cb[f], cb[f]}, cbv = ca;
                #pragma unroll
                for (int dr = 0; dr < 3; ++dr) {
                    #pragma unroll
                    for (int dc = 0; dc < 3; ++dc) {
                        const float wt = w[f * 9 + dr * 3 + dc];
                        f32x2 ia = {vv[dr][dc],     vv[dr][dc + 1]};
                        f32x2 ib = {vv[dr][dc + 2], vv[dr][dc + 3]};
                        ca  += wt * ia;
                        cbv += wt * ib;
                    }
                }
                f32x2 la  = {fmaxf(ca.x, 0.f)  + 0.01f * fminf(ca.x, 0.f),
                             fmaxf(ca.y, 0.f)  + 0.01f * fminf(ca.y, 0.f)};
                f32x2 lb2 = {fmaxf(cbv.x, 0.f) + 0.01f * fminf(cbv.x, 0.f),
                             fmaxf(cbv.y, 0.f) + 0.01f * fminf(cbv.y, 0.f)};
                pa += lw[f] * la;
                pb += lw[f] * lb2;
            }
            const unsigned word = mw[((size_t)b * S_LEN + srow) * 32 + (lane >> 3) + 8 * g];
            const unsigned nib  = (word >> ((lane & 7) * 4)) & 0xFu;
            float pre[4] = {pa.x, pa.y, pb.x, pb.y};
            #pragma unroll
            for (int i = 0; i < 4; ++i)
                if (!((nib >> i) & 1u)) pre[i] = -1e30f;
            float pv[4];
            #pragma unroll
            for (int i = 0; i < 4; ++i) { pv[i] = __expf(pre[i]); ls += pv[i]; }
            short4v hv = {(short)rne_bf16(pv[0]), (short)rne_bf16(pv[1]),
                          (short)rne_bf16(pv[2]), (short)rne_bf16(pv[3])};
            *(short4v*)&pP[r * PSTR + c0] = hv;
        }
        // wave-local row sum (row == wave)
        #pragma unroll
        for (int off = 1; off < 64; off <<= 1) ls += __shfl_xor(ls, off);
        if (lane == 0) lS[r] = ls;
        __syncthreads();
    }

    // ---- Phase C: PV. wave w: d0=(w&3)*16, t-chunks (w>>2)*16 .. +15 -------
    const int d0 = (wave & 3) * 16;
    const int th = wave >> 2;
    f32x4 O = {0.f, 0.f, 0.f, 0.f};
    #pragma unroll 4
    for (int i = 0; i < 16; ++i) {
        const int c = th * 16 + i;
        short8 ph = *(const short8*)&pP[m * PSTR + c * 32 + quad * 8];
        const size_t vb = (((size_t)bh * 128 + c * 4 + quad) * 64 + d0 + m) * 8;
        short8 vh = *(const short8*)(vhi + vb);
        short8 vl = *(const short8*)(vlo + vb);
        O = __builtin_amdgcn_mfma_f32_16x16x32_bf16(ph, vh, O, 0, 0, 0);
        O = __builtin_amdgcn_mfma_f32_16x16x32_bf16(ph, vl, O, 0, 0, 0);
    }
    if (wave < 4) {
        #pragma unroll
        for (int r = 0; r < 4; ++r) oBuf[quad * 4 + r][d0 + m] = O[r];
    }
    __syncthreads();
    if (wave >= 4) {
        #pragma unroll
        for (int r = 0; r < 4; ++r) {
            const int br = quad * 4 + r;
            out[((size_t)bh * S_LEN + s0 + br) * D_DIM + d0 + m] =
                (O[r] + oBuf[br][d0 + m]) / lS[br];
        }
    }
}

extern "C" void kernel_launch(void* const* d_in, const int* in_sizes, int n_in,
                              void* d_out, int out_size, void* d_ws, size_t ws_size,
                              hipStream_t stream) {
    const float* q      = (const float*)d_in[0];
    const float* k      = (const float*)d_in[1];
    const float* v      = (const float*)d_in[2];
    const int*   mask   = (const int*)d_in[3];
    const float* conv_w = (const float*)d_in[4];
    const float* conv_b = (const float*)d_in[5];
    const float* lin_w  = (const float*)d_in[6];
    const float* lin_b  = (const float*)d_in[7];
    float* out = (float*)d_out;

    char* wsb = (char*)d_ws;
    const size_t MB = 1024 * 1024;
    ushort_t* khi  = (ushort_t*)(wsb + 0 * MB);
    ushort_t* klo  = (ushort_t*)(wsb + 2 * MB);
    ushort_t* vhi  = (ushort_t*)(wsb + 4 * MB);
    ushort_t* vlo  = (ushort_t*)(wsb + 6 * MB);
    unsigned* mw   = (unsigned*)(wsb + 8 * MB);
    float*    dp   = (float*)(wsb + 16 * MB);      // 64 MiB

    prep<<<dim3(1024), 256, 0, stream>>>(k, v, mask, khi, klo, vhi, vlo, mw);
    qk_mfma<<<dim3(4, 64, NBH), 256, 0, stream>>>(q, khi, klo, dp);
    conv_av<<<dim3(64, NBH), 512, 0, stream>>>(
        dp, mw, vhi, vlo, conv_w, conv_b, lin_w, lin_b, out);
}